// Round 6
// baseline (200.921 us; speedup 1.0000x reference)
//
#include <hip/hip_runtime.h>
#include <math.h>

// FastGTNLayer fused: out = (sum_e scale[e]*A[e]) @ X @ lin_w^T + lin_b + bias
// A: [4][8192][8192] f32, streamed once via global_load_lds DMA.
// Round 6: KT=128 -> 512B contiguous DRAM chunks (tFAW/page-activation relief),
// X fragments prefetched into REGISTERS (L2-resident), A double-buffered in LDS.

#define NN 8192
#define CH 64
#define RB 16                  // rows per block
#define KT 128                 // k-tile (512 B contiguous per (edge,row))
#define NT (NN / KT)           // 64 tiles
#define NBLK (NN / RB)         // 512 blocks

#define A_BUF_F (4 * RB * KT)  // 8192 floats = 32 KB per A buffer
#define OFF_AGG (2 * A_BUF_F)  // 16384
#define AGG_STRIDE_S 136       // shorts per agg row (272 B; bank-canonical)
#define AGG_F ((RB * AGG_STRIDE_S) / 2)       // 1088 floats
#define LDS_FLOATS (OFF_AGG + AGG_F)          // 17472 f = 69.9 KB -> 2 blk/CU
#define HT_STRIDE 68
#define XFRAGS_PER_TILE 1024   // 4wv * 4kt * 64lane uint4 = 16 KB/tile, 1 MB total

typedef __attribute__((ext_vector_type(8))) short bf16x8;
typedef __attribute__((ext_vector_type(4))) float f32x4;

__device__ __forceinline__ void dma16(const float* g, float* l) {
  __builtin_amdgcn_global_load_lds(
      (const __attribute__((address_space(1))) void*)g,
      (__attribute__((address_space(3))) void*)l, 16, 0, 0);
}

__device__ __forceinline__ unsigned f2bfu(float f) {   // fp32 -> bf16 bits, RNE
  unsigned u = __float_as_uint(f);
  return (u + 0x7FFFu + ((u >> 16) & 1u)) >> 16;
}

// X -> bf16 B-fragment layout: uint4 index = t*1024 + wv*256 + kt*64 + lane.
// u[p] holds k-pair (bk+2p, bk+2p+1) at channel wv*16+fm, bk = t*128+kt*32+fg*8.
__global__ __launch_bounds__(256)
void gtn_packX(const float* __restrict__ X, unsigned* __restrict__ ws) {
  const int F = blockIdx.x * 256 + threadIdx.x;     // 0..65535
  const int t = F >> 10, rem = F & 1023;
  const int wv = rem >> 8, kt = (rem >> 6) & 3, lane = rem & 63;
  const int fm = lane & 15, fg = lane >> 4;
  const int c = wv * 16 + fm;
  const int bk = t * KT + kt * 32 + fg * 8;
  uint4 o;
  o.x = f2bfu(X[(size_t)(bk + 0) * CH + c]) | (f2bfu(X[(size_t)(bk + 1) * CH + c]) << 16);
  o.y = f2bfu(X[(size_t)(bk + 2) * CH + c]) | (f2bfu(X[(size_t)(bk + 3) * CH + c]) << 16);
  o.z = f2bfu(X[(size_t)(bk + 4) * CH + c]) | (f2bfu(X[(size_t)(bk + 5) * CH + c]) << 16);
  o.w = f2bfu(X[(size_t)(bk + 6) * CH + c]) | (f2bfu(X[(size_t)(bk + 7) * CH + c]) << 16);
  *(uint4*)&ws[(size_t)F * 4] = o;
}

template<bool PACKED>
__global__ __launch_bounds__(256, 2)
void gtn_fused(const float* __restrict__ A, const float* __restrict__ X,
               const uint4* __restrict__ Xp,
               const float* __restrict__ Wt, const float* __restrict__ lw,
               const float* __restrict__ lb, const float* __restrict__ bias,
               float* __restrict__ out) {
  __shared__ __align__(16) float arena[LDS_FLOATS];

  const int tid = threadIdx.x;
  const int n0  = blockIdx.x * RB;

  // scale[e] = sum_c softmax(weight, axis=0)[e,c]
  float sc0, sc1, sc2, sc3;
  {
    float a0 = Wt[0], a1 = Wt[2], a2 = Wt[4], a3 = Wt[6];
    float b0 = Wt[1], b1 = Wt[3], b2 = Wt[5], b3 = Wt[7];
    float ma = fmaxf(fmaxf(a0, a1), fmaxf(a2, a3));
    float mb = fmaxf(fmaxf(b0, b1), fmaxf(b2, b3));
    float ea0 = expf(a0 - ma), ea1 = expf(a1 - ma), ea2 = expf(a2 - ma), ea3 = expf(a3 - ma);
    float eb0 = expf(b0 - mb), eb1 = expf(b1 - mb), eb2 = expf(b2 - mb), eb3 = expf(b3 - mb);
    float ra = 1.f / (ea0 + ea1 + ea2 + ea3);
    float rb = 1.f / (eb0 + eb1 + eb2 + eb3);
    sc0 = ea0 * ra + eb0 * rb;  sc1 = ea1 * ra + eb1 * rb;
    sc2 = ea2 * ra + eb2 * rb;  sc3 = ea3 * ra + eb3 * rb;
  }

  // ---- A DMA source bases (k=0): granule g = tid + i*256 (16 B each),
  //      e = g>>9, r = (g>>5)&15, kq = g&31  -> LDS linear [e][r][kq*4].
  const float* gA[8];
#pragma unroll
  for (int i = 0; i < 8; ++i) {
    const int g = tid + i * 256;
    const int e = g >> 9, r = (g >> 5) & 15, kq = g & 31;
    gA[i] = A + ((size_t)e << 26) + (size_t)(n0 + r) * NN + kq * 4;
  }

  const int rg = tid >> 4, cg = tid & 15;       // combine / finalize map
  const int lane = tid & 63, wv = tid >> 6;     // mfma map
  const int ch0 = wv * 16;
  const int fm = lane & 15, fg = lane >> 4;

  auto issueA = [&](int u, int bi) {            // 8 dma16 / thread
    const size_t koff = (size_t)u * KT;
    float* Ad = &arena[bi * A_BUF_F];
#pragma unroll
    for (int i = 0; i < 8; ++i) dma16(gA[i] + koff, Ad + (tid + i * 256) * 4);
  };

  uint4 xcur[4], xnxt[4];
  auto loadX = [&](int u, uint4* dst) {         // 4 dwordx4 / thread (L2-hot)
    if constexpr (PACKED) {
      const uint4* xb = Xp + (size_t)u * XFRAGS_PER_TILE + wv * 256 + lane;
#pragma unroll
      for (int kt = 0; kt < 4; ++kt) dst[kt] = xb[kt * 64];
    } else {
#pragma unroll
      for (int kt = 0; kt < 4; ++kt) {
        const int bk = u * KT + kt * 32 + fg * 8;
        unsigned p[4];
#pragma unroll
        for (int pj = 0; pj < 4; ++pj)
          p[pj] = f2bfu(X[(size_t)(bk + 2 * pj) * CH + ch0 + fm]) |
                  (f2bfu(X[(size_t)(bk + 2 * pj + 1) * CH + ch0 + fm]) << 16);
        dst[kt] = make_uint4(p[0], p[1], p[2], p[3]);
      }
    }
  };

  // ---- combine: agg[r][k] = sum_e sc[e]*A_e[r][k] -> bf16, m-major [16][136s]
  auto combine = [&](int bi) {
    const float* Ab = &arena[bi * A_BUF_F];
    short* aggW = (short*)&arena[OFF_AGG];
#pragma unroll
    for (int h = 0; h < 2; ++h) {               // k = h*64 + cg*4 .. +3
      float gx = 0.f, gy = 0.f, gz = 0.f, gw = 0.f;
#pragma unroll
      for (int e = 0; e < 4; ++e) {
        const float s = (e == 0) ? sc0 : (e == 1) ? sc1 : (e == 2) ? sc2 : sc3;
        float4 v = *(const float4*)&Ab[(e * RB + rg) * KT + h * 64 + cg * 4];
        gx = fmaf(s, v.x, gx); gy = fmaf(s, v.y, gy);
        gz = fmaf(s, v.z, gz); gw = fmaf(s, v.w, gw);
      }
      unsigned u0 = f2bfu(gx) | (f2bfu(gy) << 16);
      unsigned u1 = f2bfu(gz) | (f2bfu(gw) << 16);
      *(uint2*)&aggW[rg * AGG_STRIDE_S + h * 64 + cg * 4] = make_uint2(u0, u1);
    }
  };

  f32x4 acc = {0.f, 0.f, 0.f, 0.f};
  auto domfma = [&](const uint4* xf) {          // 4 x 16x16x32 per tile
    const short* aggS = (const short*)&arena[OFF_AGG];
#pragma unroll
    for (int kt = 0; kt < 4; ++kt) {
      bf16x8 af = *(const bf16x8*)&aggS[fm * AGG_STRIDE_S + kt * 32 + fg * 8];
      union { uint4 q; bf16x8 v; } xu; xu.q = xf[kt];
      acc = __builtin_amdgcn_mfma_f32_16x16x32_bf16(af, xu.v, acc, 0, 0, 0);
    }
  };

  // ---- prologue: stream = [A(0)x8, X(0)x4, A(1)x8]
  issueA(0, 0);
  loadX(0, xcur);
  issueA(1, 1);

  // ---- main loop: per iter issue [A(t+2)x8, X(t+1)x4] after combine barrier.
  // Top-wait newer-than-A(t): t<2 -> 12; steady -> 16; last -> 8. (PACKED counts;
  // fallback path uses full drains.)
  for (int t = 0; t < NT; ++t) {
    const int b = t & 1;
    if constexpr (PACKED) {
      if (t < 2)            asm volatile("s_waitcnt vmcnt(12)\n\ts_barrier" ::: "memory");
      else if (t < NT - 1)  asm volatile("s_waitcnt vmcnt(16)\n\ts_barrier" ::: "memory");
      else                  asm volatile("s_waitcnt vmcnt(8)\n\ts_barrier" ::: "memory");
    } else {
      asm volatile("s_waitcnt vmcnt(0)\n\ts_barrier" ::: "memory");
    }

    combine(b);
    asm volatile("s_waitcnt lgkmcnt(0)\n\ts_barrier" ::: "memory");

    if (t + 2 < NT) issueA(t + 2, b);
    if (t + 1 < NT) loadX(t + 1, xnxt);

    domfma(xcur);
#pragma unroll
    for (int kt = 0; kt < 4; ++kt) xcur[kt] = xnxt[kt];
  }

  // ---- finalize: H (16x64, m89 D-layout) -> LDS -> row-linear linear layer
  __syncthreads();
  float* hT = arena;                       // reuse: [16][68]
#pragma unroll
  for (int r = 0; r < 4; ++r)
    hT[(fg * 4 + r) * HT_STRIDE + ch0 + fm] = acc[r];
  __syncthreads();

  const int c0 = cg * 4;
  float s0 = lb[c0 + 0] + bias[c0 + 0];
  float s1 = lb[c0 + 1] + bias[c0 + 1];
  float s2 = lb[c0 + 2] + bias[c0 + 2];
  float s3 = lb[c0 + 3] + bias[c0 + 3];
#pragma unroll
  for (int k4 = 0; k4 < CH / 4; ++k4) {
    float4 hv = *(const float4*)&hT[rg * HT_STRIDE + k4 * 4];
    float4 w0 = *(const float4*)&lw[(size_t)(c0 + 0) * CH + k4 * 4];
    float4 w1 = *(const float4*)&lw[(size_t)(c0 + 1) * CH + k4 * 4];
    float4 w2 = *(const float4*)&lw[(size_t)(c0 + 2) * CH + k4 * 4];
    float4 w3 = *(const float4*)&lw[(size_t)(c0 + 3) * CH + k4 * 4];
    s0 += hv.x * w0.x + hv.y * w0.y + hv.z * w0.z + hv.w * w0.w;
    s1 += hv.x * w1.x + hv.y * w1.y + hv.z * w1.z + hv.w * w1.w;
    s2 += hv.x * w2.x + hv.y * w2.y + hv.z * w2.z + hv.w * w2.w;
    s3 += hv.x * w3.x + hv.y * w3.y + hv.z * w3.z + hv.w * w3.w;
  }
  *(float4*)&out[(size_t)(n0 + rg) * CH + c0] = make_float4(s0, s1, s2, s3);
}

extern "C" void kernel_launch(void* const* d_in, const int* in_sizes, int n_in,
                              void* d_out, int out_size, void* d_ws, size_t ws_size,
                              hipStream_t stream) {
  const float* A    = (const float*)d_in[0];
  const float* X    = (const float*)d_in[1];
  const float* Wt   = (const float*)d_in[2];
  const float* lw   = (const float*)d_in[3];
  const float* lb   = (const float*)d_in[4];
  const float* bias = (const float*)d_in[5];
  float* out = (float*)d_out;

  const size_t packBytes = (size_t)NT * XFRAGS_PER_TILE * 16;   // 1 MB
  if (ws_size >= packBytes) {
    gtn_packX<<<dim3(256), 256, 0, stream>>>(X, (unsigned*)d_ws);
    gtn_fused<true><<<dim3(NBLK), 256, 0, stream>>>(
        A, X, (const uint4*)d_ws, Wt, lw, lb, bias, out);
  } else {
    gtn_fused<false><<<dim3(NBLK), 256, 0, stream>>>(
        A, X, nullptr, Wt, lw, lb, bias, out);
  }
}

// Round 9
// 192.753 us; speedup vs baseline: 1.0424x; 1.0424x over previous
//
#include <hip/hip_runtime.h>
#include <math.h>

// FastGTNLayer fused: out = (sum_e scale[e]*A[e]) @ X @ lin_w^T + lin_b + bias
// A: [4][8192][8192] f32 streamed once. Round 7 (2nd resubmit, infra failures):
// A bypasses LDS entirely (zero reuse) -> plain register loads (m13-proven path),
// combine in regs, only bf16 agg goes to LDS for cross-wave MFMA. LDS 70KB ->
// 13KB, occupancy 8 -> 12 waves/CU, 1 barrier/tile. X pre-packed bf16 in d_ws.

#define NN 8192
#define CH 64
#define RB 16                  // rows per block
#define KT 128                 // k-tile
#define NT (NN / KT)           // 64 tiles
#define NBLK (NN / RB)         // 512 blocks

#define AGG_STRIDE_S 136       // shorts per agg row (272 B; 2-way banks = free)
#define AGG_HALF (RB * AGG_STRIDE_S)
#define HT_STRIDE 68
#define XFRAGS_PER_TILE 1024   // 4wv * 4kt * 64lane uint4 = 16 KB/tile, 1 MB total

typedef __attribute__((ext_vector_type(8))) short bf16x8;
typedef __attribute__((ext_vector_type(4))) float f32x4;

__device__ __forceinline__ unsigned f2bfu(float f) {   // fp32 -> bf16 bits, RNE
  unsigned u = __float_as_uint(f);
  return (u + 0x7FFFu + ((u >> 16) & 1u)) >> 16;
}

// X -> bf16 B-fragment layout: uint4 index = t*1024 + wv*256 + kt*64 + lane.
// u[p] holds k-pair (bk+2p, bk+2p+1) at channel wv*16+fm, bk = t*128+kt*32+fg*8.
__global__ __launch_bounds__(256)
void gtn_packX(const float* __restrict__ X, unsigned* __restrict__ ws) {
  const int F = blockIdx.x * 256 + threadIdx.x;     // 0..65535
  const int t = F >> 10, rem = F & 1023;
  const int wv = rem >> 8, kt = (rem >> 6) & 3, lane = rem & 63;
  const int fm = lane & 15, fg = lane >> 4;
  const int c = wv * 16 + fm;
  const int bk = t * KT + kt * 32 + fg * 8;
  uint4 o;
  o.x = f2bfu(X[(size_t)(bk + 0) * CH + c]) | (f2bfu(X[(size_t)(bk + 1) * CH + c]) << 16);
  o.y = f2bfu(X[(size_t)(bk + 2) * CH + c]) | (f2bfu(X[(size_t)(bk + 3) * CH + c]) << 16);
  o.z = f2bfu(X[(size_t)(bk + 4) * CH + c]) | (f2bfu(X[(size_t)(bk + 5) * CH + c]) << 16);
  o.w = f2bfu(X[(size_t)(bk + 6) * CH + c]) | (f2bfu(X[(size_t)(bk + 7) * CH + c]) << 16);
  *(uint4*)&ws[(size_t)F * 4] = o;
}

template<bool PACKED>
__global__ __launch_bounds__(256, 3)
void gtn_fused(const float* __restrict__ A, const float* __restrict__ X,
               const uint4* __restrict__ Xp,
               const float* __restrict__ Wt, const float* __restrict__ lw,
               const float* __restrict__ lb, const float* __restrict__ bias,
               float* __restrict__ out) {
  __shared__ __align__(16) short aggS[2][AGG_HALF];     // 2 x 4352 B
  __shared__ __align__(16) float hT[RB * HT_STRIDE];    // finalize scratch

  const int tid = threadIdx.x;
  const int n0  = blockIdx.x * RB;

  // scale[e] = sum_c softmax(weight, axis=0)[e,c]
  float sc0, sc1, sc2, sc3;
  {
    float a0 = Wt[0], a1 = Wt[2], a2 = Wt[4], a3 = Wt[6];
    float b0 = Wt[1], b1 = Wt[3], b2 = Wt[5], b3 = Wt[7];
    float ma = fmaxf(fmaxf(a0, a1), fmaxf(a2, a3));
    float mb = fmaxf(fmaxf(b0, b1), fmaxf(b2, b3));
    float ea0 = expf(a0 - ma), ea1 = expf(a1 - ma), ea2 = expf(a2 - ma), ea3 = expf(a3 - ma);
    float eb0 = expf(b0 - mb), eb1 = expf(b1 - mb), eb2 = expf(b2 - mb), eb3 = expf(b3 - mb);
    float ra = 1.f / (ea0 + ea1 + ea2 + ea3);
    float rb = 1.f / (eb0 + eb1 + eb2 + eb3);
    sc0 = ea0 * ra + eb0 * rb;  sc1 = ea1 * ra + eb1 * rb;
    sc2 = ea2 * ra + eb2 * rb;  sc3 = ea3 * ra + eb3 * rb;
  }

  const int rg = tid >> 4, cg = tid & 15;       // combine map: (row, k-quad)
  const int lane = tid & 63, wv = tid >> 6;     // mfma map
  const int ch0 = wv * 16;
  const int fm = lane & 15, fg = lane >> 4;

  // thread's fixed A offset (floats): row base + k-quad; +t*KT+h*64 per use.
  const unsigned rowOff = (unsigned)((n0 + rg) * NN + cg * 4);

  // load A tile t into 8 float4 regs: d[e*2+h] = A_e[row][t*128 + h*64 + cg*4]
  auto loadA = [&](int t, float4* d) {
    const unsigned tOff = rowOff + (unsigned)(t * KT);
#pragma unroll
    for (int e = 0; e < 4; ++e) {
      const float* Ae = A + ((size_t)e << 26);
#pragma unroll
      for (int h = 0; h < 2; ++h)
        d[e * 2 + h] = *(const float4*)(Ae + tOff + h * 64);
    }
  };

  // load X tile t fragments (L2-hot)
  auto loadX = [&](int t, uint4* dst) {
    if constexpr (PACKED) {
      const uint4* xb = Xp + (size_t)t * XFRAGS_PER_TILE + wv * 256 + lane;
#pragma unroll
      for (int kt = 0; kt < 4; ++kt) dst[kt] = xb[kt * 64];
    } else {
#pragma unroll
      for (int kt = 0; kt < 4; ++kt) {
        const int bk = t * KT + kt * 32 + fg * 8;
        unsigned p[4];
#pragma unroll
        for (int pj = 0; pj < 4; ++pj)
          p[pj] = f2bfu(X[(size_t)(bk + 2 * pj) * CH + ch0 + fm]) |
                  (f2bfu(X[(size_t)(bk + 2 * pj + 1) * CH + ch0 + fm]) << 16);
        dst[kt] = make_uint4(p[0], p[1], p[2], p[3]);
      }
    }
  };

  // combine in regs -> bf16 agg[rg][k] in LDS buffer b
  auto combine = [&](const float4* a, int b) {
#pragma unroll
    for (int h = 0; h < 2; ++h) {
      float4 v0 = a[0 + h], v1 = a[2 + h], v2 = a[4 + h], v3 = a[6 + h];
      float gx = fmaf(sc3, v3.x, fmaf(sc2, v2.x, fmaf(sc1, v1.x, sc0 * v0.x)));
      float gy = fmaf(sc3, v3.y, fmaf(sc2, v2.y, fmaf(sc1, v1.y, sc0 * v0.y)));
      float gz = fmaf(sc3, v3.z, fmaf(sc2, v2.z, fmaf(sc1, v1.z, sc0 * v0.z)));
      float gw = fmaf(sc3, v3.w, fmaf(sc2, v2.w, fmaf(sc1, v1.w, sc0 * v0.w)));
      unsigned u0 = f2bfu(gx) | (f2bfu(gy) << 16);
      unsigned u1 = f2bfu(gz) | (f2bfu(gw) << 16);
      *(uint2*)&aggS[b][rg * AGG_STRIDE_S + h * 64 + cg * 4] = make_uint2(u0, u1);
    }
  };

  f32x4 acc = {0.f, 0.f, 0.f, 0.f};
  auto domfma = [&](int b, const uint4* xf) {   // 4 x 16x16x32 per tile
#pragma unroll
    for (int kt = 0; kt < 4; ++kt) {
      bf16x8 af = *(const bf16x8*)&aggS[b][fm * AGG_STRIDE_S + kt * 32 + fg * 8];
      union { uint4 q; bf16x8 v; } xu; xu.q = xf[kt];
      acc = __builtin_amdgcn_mfma_f32_16x16x32_bf16(af, xu.v, acc, 0, 0, 0);
    }
  };

  // ---- ping-pong register staging, unroll-2 (static indexing), 1 barrier/tile
  float4 aA[8], aB[8];
  uint4  xA[4], xB[4];
  loadA(0, aA); loadX(0, xA);

  for (int t = 0; t < NT; t += 2) {
    loadA(t + 1, aB); loadX(t + 1, xB);        // prefetch; hides under combine+mfma
    combine(aA, 0);
    asm volatile("s_waitcnt lgkmcnt(0)\n\ts_barrier" ::: "memory");
    domfma(0, xA);

    if (t + 2 < NT) { loadA(t + 2, aA); loadX(t + 2, xA); }
    combine(aB, 1);
    asm volatile("s_waitcnt lgkmcnt(0)\n\ts_barrier" ::: "memory");
    domfma(1, xB);
  }

  // ---- finalize: H (16x64, m89 D-layout) -> LDS -> row-linear linear layer
  __syncthreads();
#pragma unroll
  for (int r = 0; r < 4; ++r)
    hT[(fg * 4 + r) * HT_STRIDE + ch0 + fm] = acc[r];
  __syncthreads();

  const int c0 = cg * 4;
  float s0 = lb[c0 + 0] + bias[c0 + 0];
  float s1 = lb[c0 + 1] + bias[c0 + 1];
  float s2 = lb[c0 + 2] + bias[c0 + 2];
  float s3 = lb[c0 + 3] + bias[c0 + 3];
#pragma unroll
  for (int k4 = 0; k4 < CH / 4; ++k4) {
    float4 hv = *(const float4*)&hT[rg * HT_STRIDE + k4 * 4];
    float4 w0 = *(const float4*)&lw[(size_t)(c0 + 0) * CH + k4 * 4];
    float4 w1 = *(const float4*)&lw[(size_t)(c0 + 1) * CH + k4 * 4];
    float4 w2 = *(const float4*)&lw[(size_t)(c0 + 2) * CH + k4 * 4];
    float4 w3 = *(const float4*)&lw[(size_t)(c0 + 3) * CH + k4 * 4];
    s0 += hv.x * w0.x + hv.y * w0.y + hv.z * w0.z + hv.w * w0.w;
    s1 += hv.x * w1.x + hv.y * w1.y + hv.z * w1.z + hv.w * w1.w;
    s2 += hv.x * w2.x + hv.y * w2.y + hv.z * w2.z + hv.w * w2.w;
    s3 += hv.x * w3.x + hv.y * w3.y + hv.z * w3.z + hv.w * w3.w;
  }
  *(float4*)&out[(size_t)(n0 + rg) * CH + c0] = make_float4(s0, s1, s2, s3);
}

extern "C" void kernel_launch(void* const* d_in, const int* in_sizes, int n_in,
                              void* d_out, int out_size, void* d_ws, size_t ws_size,
                              hipStream_t stream) {
  const float* A    = (const float*)d_in[0];
  const float* X    = (const float*)d_in[1];
  const float* Wt   = (const float*)d_in[2];
  const float* lw   = (const float*)d_in[3];
  const float* lb   = (const float*)d_in[4];
  const float* bias = (const float*)d_in[5];
  float* out = (float*)d_out;

  const size_t packBytes = (size_t)NT * XFRAGS_PER_TILE * 16;   // 1 MB
  if (ws_size >= packBytes) {
    gtn_packX<<<dim3(256), 256, 0, stream>>>(X, (unsigned*)d_ws);
    gtn_fused<true><<<dim3(NBLK), 256, 0, stream>>>(
        A, X, (const uint4*)d_ws, Wt, lw, lb, bias, out);
  } else {
    gtn_fused<false><<<dim3(NBLK), 256, 0, stream>>>(
        A, X, nullptr, Wt, lw, lb, bias, out);
  }
}

// Round 11
// 191.902 us; speedup vs baseline: 1.0470x; 1.0044x over previous
//
#include <hip/hip_runtime.h>
#include <math.h>

// FastGTNLayer fused: out = (sum_e scale[e]*A[e]) @ X @ lin_w^T + lin_b + bias
// A: [4][8192][8192] f32 streamed once (register loads, nt-hint). Round 11
// (r10 compile-fix: nontemporal_load needs ext_vector_type, not HIP float4):
// KSPLIT=2 -> 1024 blocks = 4 blocks/CU = 16 waves/CU. Partial H -> d_ws,
// finalize kernel sums + applies linear. X single-buffered, loaded late (L2-hot).

#define NN 8192
#define CH 64
#define RB 16                  // rows per block
#define KT 128                 // k-tile
#define NT (NN / KT)           // 64 tiles total over K
#define NBLK (NN / RB)         // 512 row-blocks

#define AGG_STRIDE_S 136       // shorts per agg row (272 B; 2-way banks = free)
#define AGG_HALF (RB * AGG_STRIDE_S)
#define HT_STRIDE 68
#define XFRAGS_PER_TILE 1024   // 4wv * 4kt * 64lane uint4 = 16 KB/tile, 1 MB total
#define WS_PARTIAL_OFF (4u << 20)   // partial H at d_ws + 4 MB (Xp at offset 0)

typedef __attribute__((ext_vector_type(8))) short bf16x8;
typedef __attribute__((ext_vector_type(4))) float f32x4;

__device__ __forceinline__ unsigned f2bfu(float f) {   // fp32 -> bf16 bits, RNE
  unsigned u = __float_as_uint(f);
  return (u + 0x7FFFu + ((u >> 16) & 1u)) >> 16;
}

// X -> bf16 B-fragment layout: uint4 index = t*1024 + wv*256 + kt*64 + lane.
// u[p] holds k-pair (bk+2p, bk+2p+1) at channel wv*16+fm, bk = t*128+kt*32+fg*8.
__global__ __launch_bounds__(256)
void gtn_packX(const float* __restrict__ X, unsigned* __restrict__ ws) {
  const int F = blockIdx.x * 256 + threadIdx.x;     // 0..65535
  const int t = F >> 10, rem = F & 1023;
  const int wv = rem >> 8, kt = (rem >> 6) & 3, lane = rem & 63;
  const int fm = lane & 15, fg = lane >> 4;
  const int c = wv * 16 + fm;
  const int bk = t * KT + kt * 32 + fg * 8;
  uint4 o;
  o.x = f2bfu(X[(size_t)(bk + 0) * CH + c]) | (f2bfu(X[(size_t)(bk + 1) * CH + c]) << 16);
  o.y = f2bfu(X[(size_t)(bk + 2) * CH + c]) | (f2bfu(X[(size_t)(bk + 3) * CH + c]) << 16);
  o.z = f2bfu(X[(size_t)(bk + 4) * CH + c]) | (f2bfu(X[(size_t)(bk + 5) * CH + c]) << 16);
  o.w = f2bfu(X[(size_t)(bk + 6) * CH + c]) | (f2bfu(X[(size_t)(bk + 7) * CH + c]) << 16);
  *(uint4*)&ws[(size_t)F * 4] = o;
}

template<bool PACKED, int KSPLIT>
__global__ __launch_bounds__(256, 4)
void gtn_fused(const float* __restrict__ A, const float* __restrict__ X,
               const uint4* __restrict__ Xp, float* __restrict__ partial,
               const float* __restrict__ Wt, const float* __restrict__ lw,
               const float* __restrict__ lb, const float* __restrict__ bias,
               float* __restrict__ out) {
  constexpr int NT2 = NT / KSPLIT;
  __shared__ __align__(16) short aggS[2][AGG_HALF];     // 2 x 4352 B
  __shared__ __align__(16) float hT[RB * HT_STRIDE];    // finalize scratch (KSPLIT==1)

  const int tid = threadIdx.x;
  const int mt  = blockIdx.x % NBLK;        // row-block
  const int ks  = blockIdx.x / NBLK;        // k-split half
  const int n0  = mt * RB;
  const int tBase = ks * NT2;

  // scale[e] = sum_c softmax(weight, axis=0)[e,c]
  float sc0, sc1, sc2, sc3;
  {
    float a0 = Wt[0], a1 = Wt[2], a2 = Wt[4], a3 = Wt[6];
    float b0 = Wt[1], b1 = Wt[3], b2 = Wt[5], b3 = Wt[7];
    float ma = fmaxf(fmaxf(a0, a1), fmaxf(a2, a3));
    float mb = fmaxf(fmaxf(b0, b1), fmaxf(b2, b3));
    float ea0 = expf(a0 - ma), ea1 = expf(a1 - ma), ea2 = expf(a2 - ma), ea3 = expf(a3 - ma);
    float eb0 = expf(b0 - mb), eb1 = expf(b1 - mb), eb2 = expf(b2 - mb), eb3 = expf(b3 - mb);
    float ra = 1.f / (ea0 + ea1 + ea2 + ea3);
    float rb = 1.f / (eb0 + eb1 + eb2 + eb3);
    sc0 = ea0 * ra + eb0 * rb;  sc1 = ea1 * ra + eb1 * rb;
    sc2 = ea2 * ra + eb2 * rb;  sc3 = ea3 * ra + eb3 * rb;
  }

  const int rg = tid >> 4, cg = tid & 15;       // combine map: (row, k-quad)
  const int lane = tid & 63, wv = tid >> 6;     // mfma map
  const int ch0 = wv * 16;
  const int fm = lane & 15, fg = lane >> 4;

  const unsigned rowOff = (unsigned)((n0 + rg) * NN + cg * 4);

  // load A tile (local t) into 8 f32x4 regs, nt-hint (stream-once: keep Xp in L2)
  auto loadA = [&](int t, f32x4* d) {
    const unsigned tOff = rowOff + (unsigned)((tBase + t) * KT);
#pragma unroll
    for (int e = 0; e < 4; ++e) {
      const float* Ae = A + ((size_t)e << 26);
#pragma unroll
      for (int h = 0; h < 2; ++h)
        d[e * 2 + h] = __builtin_nontemporal_load((const f32x4*)(Ae + tOff + h * 64));
    }
  };

  // load X fragments for local tile t (L2-hot; issued just before mfma)
  auto loadX = [&](int t, uint4* dst) {
    if constexpr (PACKED) {
      const uint4* xb = Xp + (size_t)(tBase + t) * XFRAGS_PER_TILE + wv * 256 + lane;
#pragma unroll
      for (int kt = 0; kt < 4; ++kt) dst[kt] = xb[kt * 64];
    } else {
#pragma unroll
      for (int kt = 0; kt < 4; ++kt) {
        const int bk = (tBase + t) * KT + kt * 32 + fg * 8;
        unsigned p[4];
#pragma unroll
        for (int pj = 0; pj < 4; ++pj)
          p[pj] = f2bfu(X[(size_t)(bk + 2 * pj) * CH + ch0 + fm]) |
                  (f2bfu(X[(size_t)(bk + 2 * pj + 1) * CH + ch0 + fm]) << 16);
        dst[kt] = make_uint4(p[0], p[1], p[2], p[3]);
      }
    }
  };

  // combine in regs -> bf16 agg[rg][k] in LDS buffer b
  auto combine = [&](const f32x4* a, int b) {
#pragma unroll
    for (int h = 0; h < 2; ++h) {
      f32x4 v0 = a[0 + h], v1 = a[2 + h], v2 = a[4 + h], v3 = a[6 + h];
      float gx = fmaf(sc3, v3.x, fmaf(sc2, v2.x, fmaf(sc1, v1.x, sc0 * v0.x)));
      float gy = fmaf(sc3, v3.y, fmaf(sc2, v2.y, fmaf(sc1, v1.y, sc0 * v0.y)));
      float gz = fmaf(sc3, v3.z, fmaf(sc2, v2.z, fmaf(sc1, v1.z, sc0 * v0.z)));
      float gw = fmaf(sc3, v3.w, fmaf(sc2, v2.w, fmaf(sc1, v1.w, sc0 * v0.w)));
      unsigned u0 = f2bfu(gx) | (f2bfu(gy) << 16);
      unsigned u1 = f2bfu(gz) | (f2bfu(gw) << 16);
      *(uint2*)&aggS[b][rg * AGG_STRIDE_S + h * 64 + cg * 4] = make_uint2(u0, u1);
    }
  };

  f32x4 acc = {0.f, 0.f, 0.f, 0.f};
  auto domfma = [&](int b, const uint4* xf) {   // 4 x 16x16x32 per tile
#pragma unroll
    for (int kt = 0; kt < 4; ++kt) {
      bf16x8 af = *(const bf16x8*)&aggS[b][fm * AGG_STRIDE_S + kt * 32 + fg * 8];
      union { uint4 q; bf16x8 v; } xu; xu.q = xf[kt];
      acc = __builtin_amdgcn_mfma_f32_16x16x32_bf16(af, xu.v, acc, 0, 0, 0);
    }
  };

  // ---- ping-pong A staging (unroll-2, static idx), late single-buffer X.
  // Barrier pairing proven in r7/r9; aggS WAR safety via lgkmcnt(0) at barriers.
  f32x4 aA[8], aB[8];
  uint4 xC[4];
  loadA(0, aA);

  for (int t = 0; t < NT2; t += 2) {
    loadA(t + 1, aB);                          // HBM prefetch hides under combine+mfma
    combine(aA, 0);
    asm volatile("s_waitcnt lgkmcnt(0)\n\ts_barrier" ::: "memory");
    loadX(t, xC);
    domfma(0, xC);

    if (t + 2 < NT2) loadA(t + 2, aA);
    combine(aB, 1);
    asm volatile("s_waitcnt lgkmcnt(0)\n\ts_barrier" ::: "memory");
    loadX(t + 1, xC);
    domfma(1, xC);
  }

  if constexpr (KSPLIT == 2) {
    // ---- write partial H (m89 D-layout -> row-linear f32), no atomics
    float* P = partial + ((size_t)ks * NN + n0) * CH;
#pragma unroll
    for (int r = 0; r < 4; ++r)
      P[(size_t)(fg * 4 + r) * CH + ch0 + fm] = acc[r];
  } else {
    // ---- in-block finalize: H -> LDS -> out = H @ lin_w^T + lin_b + bias
    __syncthreads();
#pragma unroll
    for (int r = 0; r < 4; ++r)
      hT[(fg * 4 + r) * HT_STRIDE + ch0 + fm] = acc[r];
    __syncthreads();

    const int c0 = cg * 4;
    float s0 = lb[c0 + 0] + bias[c0 + 0];
    float s1 = lb[c0 + 1] + bias[c0 + 1];
    float s2 = lb[c0 + 2] + bias[c0 + 2];
    float s3 = lb[c0 + 3] + bias[c0 + 3];
#pragma unroll
    for (int k4 = 0; k4 < CH / 4; ++k4) {
      float4 hv = *(const float4*)&hT[rg * HT_STRIDE + k4 * 4];
      float4 w0 = *(const float4*)&lw[(size_t)(c0 + 0) * CH + k4 * 4];
      float4 w1 = *(const float4*)&lw[(size_t)(c0 + 1) * CH + k4 * 4];
      float4 w2 = *(const float4*)&lw[(size_t)(c0 + 2) * CH + k4 * 4];
      float4 w3 = *(const float4*)&lw[(size_t)(c0 + 3) * CH + k4 * 4];
      s0 += hv.x * w0.x + hv.y * w0.y + hv.z * w0.z + hv.w * w0.w;
      s1 += hv.x * w1.x + hv.y * w1.y + hv.z * w1.z + hv.w * w1.w;
      s2 += hv.x * w2.x + hv.y * w2.y + hv.z * w2.z + hv.w * w2.w;
      s3 += hv.x * w3.x + hv.y * w3.y + hv.z * w3.z + hv.w * w3.w;
    }
    *(float4*)&out[(size_t)(n0 + rg) * CH + c0] = make_float4(s0, s1, s2, s3);
  }
}

// sum the two K-half partials + linear layer -> out
__global__ __launch_bounds__(256)
void gtn_fin(const float* __restrict__ P, const float* __restrict__ lw,
             const float* __restrict__ lb, const float* __restrict__ bias,
             float* __restrict__ out) {
  __shared__ __align__(16) float hT[RB * HT_STRIDE];
  const int tid = threadIdx.x, rg = tid >> 4, cg = tid & 15;
  const int n0 = blockIdx.x * RB;

  float4 a = *(const float4*)&P[(size_t)(n0 + rg) * CH + cg * 4];
  float4 b = *(const float4*)&P[(size_t)(NN + n0 + rg) * CH + cg * 4];
  *(float4*)&hT[rg * HT_STRIDE + cg * 4] =
      make_float4(a.x + b.x, a.y + b.y, a.z + b.z, a.w + b.w);
  __syncthreads();

  const int c0 = cg * 4;
  float s0 = lb[c0 + 0] + bias[c0 + 0];
  float s1 = lb[c0 + 1] + bias[c0 + 1];
  float s2 = lb[c0 + 2] + bias[c0 + 2];
  float s3 = lb[c0 + 3] + bias[c0 + 3];
#pragma unroll
  for (int k4 = 0; k4 < CH / 4; ++k4) {
    float4 hv = *(const float4*)&hT[rg * HT_STRIDE + k4 * 4];
    float4 w0 = *(const float4*)&lw[(size_t)(c0 + 0) * CH + k4 * 4];
    float4 w1 = *(const float4*)&lw[(size_t)(c0 + 1) * CH + k4 * 4];
    float4 w2 = *(const float4*)&lw[(size_t)(c0 + 2) * CH + k4 * 4];
    float4 w3 = *(const float4*)&lw[(size_t)(c0 + 3) * CH + k4 * 4];
    s0 += hv.x * w0.x + hv.y * w0.y + hv.z * w0.z + hv.w * w0.w;
    s1 += hv.x * w1.x + hv.y * w1.y + hv.z * w1.z + hv.w * w1.w;
    s2 += hv.x * w2.x + hv.y * w2.y + hv.z * w2.z + hv.w * w2.w;
    s3 += hv.x * w3.x + hv.y * w3.y + hv.z * w3.z + hv.w * w3.w;
  }
  *(float4*)&out[(size_t)(n0 + rg) * CH + c0] = make_float4(s0, s1, s2, s3);
}

extern "C" void kernel_launch(void* const* d_in, const int* in_sizes, int n_in,
                              void* d_out, int out_size, void* d_ws, size_t ws_size,
                              hipStream_t stream) {
  const float* A    = (const float*)d_in[0];
  const float* X    = (const float*)d_in[1];
  const float* Wt   = (const float*)d_in[2];
  const float* lw   = (const float*)d_in[3];
  const float* lb   = (const float*)d_in[4];
  const float* bias = (const float*)d_in[5];
  float* out = (float*)d_out;

  const size_t packBytes  = (size_t)NT * XFRAGS_PER_TILE * 16;          // 1 MB
  const size_t splitBytes = WS_PARTIAL_OFF + (size_t)2 * NN * CH * 4;   // 8 MB

  if (ws_size >= splitBytes) {
    float* partial = (float*)((char*)d_ws + WS_PARTIAL_OFF);
    gtn_packX<<<dim3(256), 256, 0, stream>>>(X, (unsigned*)d_ws);
    gtn_fused<true, 2><<<dim3(NBLK * 2), 256, 0, stream>>>(
        A, X, (const uint4*)d_ws, partial, Wt, lw, lb, bias, out);
    gtn_fin<<<dim3(NBLK), 256, 0, stream>>>(partial, lw, lb, bias, out);
  } else if (ws_size >= packBytes) {
    gtn_packX<<<dim3(256), 256, 0, stream>>>(X, (unsigned*)d_ws);
    gtn_fused<true, 1><<<dim3(NBLK), 256, 0, stream>>>(
        A, X, (const uint4*)d_ws, nullptr, Wt, lw, lb, bias, out);
  } else {
    gtn_fused<false, 1><<<dim3(NBLK), 256, 0, stream>>>(
        A, X, nullptr, nullptr, Wt, lw, lb, bias, out);
  }
}